// Round 3
// baseline (459.332 us; speedup 1.0000x reference)
//
#include <hip/hip_runtime.h>

// ---------- types ----------
typedef __attribute__((ext_vector_type(8))) _Float16 half8;
typedef __attribute__((ext_vector_type(4))) _Float16 half4v;
typedef __attribute__((ext_vector_type(4))) float float4v;

// MFMA wrappers. Host pass chokes on top-level __has_builtin dispatch
// (round-1 failure), so guard with __HIP_DEVICE_COMPILE__: host gets a dead
// stub, device gets the builtin (device-pass __has_builtin works).
__device__ __forceinline__ float4v mfma16x16x32_f16(half8 a, half8 b, float4v c) {
#if defined(__HIP_DEVICE_COMPILE__)
#if __has_builtin(__builtin_amdgcn_mfma_f32_16x16x32_f16)
  return __builtin_amdgcn_mfma_f32_16x16x32_f16(a, b, c, 0, 0, 0);
#elif __has_builtin(__builtin_amdgcn_mfma_f32_16x16x32f16)
  return __builtin_amdgcn_mfma_f32_16x16x32f16(a, b, c, 0, 0, 0);
#else
#error "no 16x16x32 f16 mfma"
#endif
#else
  (void)a; (void)b;
  return c;
#endif
}

__device__ __forceinline__ float4v mfma16x16x16_f16(half4v a, half4v b, float4v c) {
#if defined(__HIP_DEVICE_COMPILE__)
#if __has_builtin(__builtin_amdgcn_mfma_f32_16x16x16f16)
  return __builtin_amdgcn_mfma_f32_16x16x16f16(a, b, c, 0, 0, 0);
#elif __has_builtin(__builtin_amdgcn_mfma_f32_16x16x16_f16)
  return __builtin_amdgcn_mfma_f32_16x16x16_f16(a, b, c, 0, 0, 0);
#else
#error "no 16x16x16 f16 mfma"
#endif
#else
  (void)a; (void)b;
  return c;
#endif
}

__device__ __forceinline__ unsigned short f2h(float f) {
  union { _Float16 h; unsigned short u; } v;
  v.h = (_Float16)f;
  return v.u;
}
__device__ __forceinline__ float h2f(unsigned u) {
  union { unsigned short u; _Float16 h; } v;
  v.u = (unsigned short)u;
  return (float)v.h;
}

// ---------- fp32 -> fp16 convert ----------
__global__ __launch_bounds__(256) void cvt_f32_f16(const float* __restrict__ in,
                                                   unsigned short* __restrict__ out, int n4) {
  int i = blockIdx.x * 256 + threadIdx.x;
  if (i >= n4) return;
  float4 v = ((const float4*)in)[i];
  uint2 o;
  o.x = (unsigned)f2h(v.x) | ((unsigned)f2h(v.y) << 16);
  o.y = (unsigned)f2h(v.z) | ((unsigned)f2h(v.w) << 16);
  ((uint2*)out)[i] = o;
}

// ---------- QKV projection GEMM: C = X @ W[widx]^T + b[widx], fp16 in/out ----------
// grid (4 n-tiles, 96 m-tiles, 3 {q,k,v}); block 256 (4 waves, 2x2 of 64x64)
__global__ __launch_bounds__(256) void gemm_qkv(
    const unsigned short* __restrict__ X,
    const unsigned short* __restrict__ Wq, const unsigned short* __restrict__ Wk,
    const unsigned short* __restrict__ Wv,
    const float* __restrict__ bq, const float* __restrict__ bk, const float* __restrict__ bv,
    unsigned short* __restrict__ Cq, unsigned short* __restrict__ Ck, unsigned short* __restrict__ Cv,
    int wsel_mode, int widx_fixed) {
  const int nt = blockIdx.x, mt = blockIdx.y, z = blockIdx.z;
  const unsigned short* W = (z == 0) ? Wq : ((z == 1) ? Wk : Wv);
  const float* bias = (z == 0) ? bq : ((z == 1) ? bk : bv);
  unsigned short* C = (z == 0) ? Cq : ((z == 1) ? Ck : Cv);
  const int widx = wsel_mode ? (1 + (mt % 3)) : widx_fixed;
  W += (size_t)widx * 512 * 512;
  bias += widx * 512;

  __shared__ __align__(16) unsigned short Xs[128][72];
  __shared__ __align__(16) unsigned short Wt[128][72];
  const int tid = threadIdx.x, lane = tid & 63, w = tid >> 6;
  const int col = lane & 15, grp = lane >> 4;
  const int wm = (w >> 1) * 64, wn = (w & 1) * 64;

  const float4v zero4 = {0.f, 0.f, 0.f, 0.f};
  float4v acc[4][4];
#pragma unroll
  for (int i = 0; i < 4; ++i)
#pragma unroll
    for (int j = 0; j < 4; ++j) acc[i][j] = zero4;

  const int lr = tid >> 3, lc = (tid & 7) * 8;
  for (int k0 = 0; k0 < 512; k0 += 64) {
#pragma unroll
    for (int p = 0; p < 4; ++p) {
      *(half8*)&Xs[lr + 32 * p][lc] =
          *(const half8*)&X[(size_t)(mt * 128 + lr + 32 * p) * 512 + k0 + lc];
      *(half8*)&Wt[lr + 32 * p][lc] =
          *(const half8*)&W[(size_t)(nt * 128 + lr + 32 * p) * 512 + k0 + lc];
    }
    __syncthreads();
#pragma unroll
    for (int kk = 0; kk < 64; kk += 32) {
      half8 af[4], bf[4];
#pragma unroll
      for (int i = 0; i < 4; ++i) af[i] = *(const half8*)&Xs[wm + i * 16 + col][kk + grp * 8];
#pragma unroll
      for (int j = 0; j < 4; ++j) bf[j] = *(const half8*)&Wt[wn + j * 16 + col][kk + grp * 8];
#pragma unroll
      for (int i = 0; i < 4; ++i)
#pragma unroll
        for (int j = 0; j < 4; ++j)
          acc[i][j] = mfma16x16x32_f16(af[i], bf[j], acc[i][j]);
    }
    __syncthreads();
  }
#pragma unroll
  for (int j = 0; j < 4; ++j) {
    const int n = nt * 128 + wn + j * 16 + col;
    const float bj = bias[n];
#pragma unroll
    for (int i = 0; i < 4; ++i)
#pragma unroll
      for (int r = 0; r < 4; ++r) {
        const int m = mt * 128 + wm + i * 16 + grp * 4 + r;
        C[(size_t)m * 512 + n] = f2h(acc[i][j][r] + bj);
      }
  }
}

// ---------- fusion GEMM: diff = Xdiff @ W^T ; out = tl2 + (tl1-tl2)*sigmoid(diff) ----------
__global__ __launch_bounds__(256) void gemm_fusion(
    const unsigned short* __restrict__ X, const unsigned short* __restrict__ Wf,
    const float* __restrict__ tl1, const float* __restrict__ tl2, float* __restrict__ outp) {
  const int nt = blockIdx.x, mt = blockIdx.y;
  __shared__ __align__(16) unsigned short Xs[128][72];
  __shared__ __align__(16) unsigned short Wt[128][72];
  const int tid = threadIdx.x, lane = tid & 63, w = tid >> 6;
  const int col = lane & 15, grp = lane >> 4;
  const int wm = (w >> 1) * 64, wn = (w & 1) * 64;

  const float4v zero4 = {0.f, 0.f, 0.f, 0.f};
  float4v acc[4][4];
#pragma unroll
  for (int i = 0; i < 4; ++i)
#pragma unroll
    for (int j = 0; j < 4; ++j) acc[i][j] = zero4;

  const int lr = tid >> 3, lc = (tid & 7) * 8;
  for (int k0 = 0; k0 < 512; k0 += 64) {
#pragma unroll
    for (int p = 0; p < 4; ++p) {
      *(half8*)&Xs[lr + 32 * p][lc] =
          *(const half8*)&X[(size_t)(mt * 128 + lr + 32 * p) * 512 + k0 + lc];
      *(half8*)&Wt[lr + 32 * p][lc] =
          *(const half8*)&Wf[(size_t)(nt * 128 + lr + 32 * p) * 512 + k0 + lc];
    }
    __syncthreads();
#pragma unroll
    for (int kk = 0; kk < 64; kk += 32) {
      half8 af[4], bf[4];
#pragma unroll
      for (int i = 0; i < 4; ++i) af[i] = *(const half8*)&Xs[wm + i * 16 + col][kk + grp * 8];
#pragma unroll
      for (int j = 0; j < 4; ++j) bf[j] = *(const half8*)&Wt[wn + j * 16 + col][kk + grp * 8];
#pragma unroll
      for (int i = 0; i < 4; ++i)
#pragma unroll
        for (int j = 0; j < 4; ++j)
          acc[i][j] = mfma16x16x32_f16(af[i], bf[j], acc[i][j]);
    }
    __syncthreads();
  }
#pragma unroll
  for (int j = 0; j < 4; ++j) {
    const int n = nt * 128 + wn + j * 16 + col;
#pragma unroll
    for (int i = 0; i < 4; ++i)
#pragma unroll
      for (int r = 0; r < 4; ++r) {
        const int m = mt * 128 + wm + i * 16 + grp * 4 + r;
        const size_t off = (size_t)m * 512 + n;
        const float t1 = tl1[off], t2 = tl2[off];
        const float sg = 1.0f / (1.0f + __expf(-acc[i][j][r]));
        outp[off] = t2 + (t1 - t2) * sg;
      }
  }
}

// ---------- attention: one workgroup per (b, h[, chunk]) ----------
// S[t,s] = sum_dd K[dd,t]*V[dd,s] (scaled by temp)
// M[t] = max_s S; Z'[t] = sum_s exp(S-M);  P'[t,s] = exp(S-M) in fp16 (<=1)
// out[dd,s] = sum_t (Q[dd,t]/Z'[t]) * P'[t,s]
template <int T>
__global__ __launch_bounds__(256) void attn_kernel(
    const unsigned short* __restrict__ Qb, const unsigned short* __restrict__ Kb,
    const unsigned short* __restrict__ Vb, const float* __restrict__ temp_base,
    const float* add_src,  // no restrict: may alias outp (in-place tl2)
    float* outp, int chunk_elems,
    const float* __restrict__ tl1_src, unsigned short* __restrict__ diff_out) {
  constexpr int NT = T / 16;
  constexpr int NSW = (T / 16) / 4;
  constexpr int SLAB = T * 32;
  const int h = blockIdx.x, b = blockIdx.y, cb = blockIdx.z;
  const int base = b * (384 * 512) + cb * chunk_elems + h * SLAB;
  const float tscale = temp_base[cb * 16 + h];

  __shared__ __align__(16) unsigned short Kt[T][40];  // [t][dd], fp16; row = 80B (16B-mult)
  __shared__ __align__(16) unsigned short Vt[T][40];  // [s][dd]
  __shared__ __align__(16) float Mrow[T];
  __shared__ __align__(16) float Zr[T];
  __shared__ __align__(16) float Part[4][T];

  const int tid = threadIdx.x, lane = tid & 63, w = tid >> 6;
  const int col = lane & 15, grp = lane >> 4;

  // --- load K, V slabs ([dd][t] in memory) transposed into LDS ---
  {
    const unsigned short* Ksl = Kb + base;
    const unsigned short* Vsl = Vb + base;
    const int dd = w * 8 + (lane >> 3);
    const int tof = (lane & 7) * 8;
#pragma unroll
    for (int tp = 0; tp < T / 64; ++tp) {
      const int t0 = tp * 64 + tof;
      uint4 kv = *(const uint4*)(Ksl + dd * T + t0);
      uint4 vv = *(const uint4*)(Vsl + dd * T + t0);
      unsigned short ku[8] = {(unsigned short)kv.x, (unsigned short)(kv.x >> 16),
                              (unsigned short)kv.y, (unsigned short)(kv.y >> 16),
                              (unsigned short)kv.z, (unsigned short)(kv.z >> 16),
                              (unsigned short)kv.w, (unsigned short)(kv.w >> 16)};
      unsigned short vu[8] = {(unsigned short)vv.x, (unsigned short)(vv.x >> 16),
                              (unsigned short)vv.y, (unsigned short)(vv.y >> 16),
                              (unsigned short)vv.z, (unsigned short)(vv.z >> 16),
                              (unsigned short)vv.w, (unsigned short)(vv.w >> 16)};
#pragma unroll
      for (int j = 0; j < 8; ++j) {
        Kt[t0 + j][dd] = ku[j];
        Vt[t0 + j][dd] = vu[j];
      }
    }
  }
  __syncthreads();

  const float4v zero4 = {0.f, 0.f, 0.f, 0.f};
  // cache this wave's V fragments (strips st = w, w+4, ...)
  half8 vfr[NSW];
#pragma unroll
  for (int si = 0; si < NSW; ++si)
    vfr[si] = *(const half8*)&Vt[(w + si * 4) * 16 + col][grp * 8];

  // --- pass A: row max M[t] of S*tscale ---
  for (int tt = 0; tt < NT; ++tt) {
    half8 kf = *(const half8*)&Kt[tt * 16 + col][grp * 8];
    float m0 = -3e38f, m1 = -3e38f, m2 = -3e38f, m3 = -3e38f;
#pragma unroll
    for (int si = 0; si < NSW; ++si) {
      float4v s = mfma16x16x32_f16(kf, vfr[si], zero4);
      m0 = fmaxf(m0, s[0] * tscale);
      m1 = fmaxf(m1, s[1] * tscale);
      m2 = fmaxf(m2, s[2] * tscale);
      m3 = fmaxf(m3, s[3] * tscale);
    }
#pragma unroll
    for (int m = 1; m < 16; m <<= 1) {
      m0 = fmaxf(m0, __shfl_xor(m0, m));
      m1 = fmaxf(m1, __shfl_xor(m1, m));
      m2 = fmaxf(m2, __shfl_xor(m2, m));
      m3 = fmaxf(m3, __shfl_xor(m3, m));
    }
    if (col == 0) {
      const int tb = tt * 16 + grp * 4;
      Part[w][tb + 0] = m0;
      Part[w][tb + 1] = m1;
      Part[w][tb + 2] = m2;
      Part[w][tb + 3] = m3;
    }
  }
  __syncthreads();
  for (int t = tid; t < T; t += 256)
    Mrow[t] = fmaxf(fmaxf(Part[0][t], Part[1][t]), fmaxf(Part[2][t], Part[3][t]));
  __syncthreads();

  // --- pass B: Z'[t] = sum_s exp(S*tscale - M[t]) ---
  for (int tt = 0; tt < NT; ++tt) {
    half8 kf = *(const half8*)&Kt[tt * 16 + col][grp * 8];
    const int tb = tt * 16 + grp * 4;
    float4 mr = *(const float4*)&Mrow[tb];
    float z0 = 0.f, z1 = 0.f, z2 = 0.f, z3 = 0.f;
#pragma unroll
    for (int si = 0; si < NSW; ++si) {
      float4v s = mfma16x16x32_f16(kf, vfr[si], zero4);
      z0 += __expf(s[0] * tscale - mr.x);
      z1 += __expf(s[1] * tscale - mr.y);
      z2 += __expf(s[2] * tscale - mr.z);
      z3 += __expf(s[3] * tscale - mr.w);
    }
#pragma unroll
    for (int m = 1; m < 16; m <<= 1) {
      z0 += __shfl_xor(z0, m);
      z1 += __shfl_xor(z1, m);
      z2 += __shfl_xor(z2, m);
      z3 += __shfl_xor(z3, m);
    }
    if (col == 0) {
      Part[w][tb + 0] = z0;
      Part[w][tb + 1] = z1;
      Part[w][tb + 2] = z2;
      Part[w][tb + 3] = z3;
    }
  }
  __syncthreads();
  for (int t = tid; t < T; t += 256)
    Zr[t] = 1.0f / (Part[0][t] + Part[1][t] + Part[2][t] + Part[3][t]);
  __syncthreads();

  // --- pass C: out = (Q/Z') @ P' ---
  const unsigned short* Qsl = Qb + base;
  float4v oacc[NSW][2];
#pragma unroll
  for (int si = 0; si < NSW; ++si) {
    oacc[si][0] = zero4;
    oacc[si][1] = zero4;
  }
  for (int tt = 0; tt < NT; ++tt) {
    half8 kf = *(const half8*)&Kt[tt * 16 + col][grp * 8];
    const int toff = tt * 16 + grp * 4;
    float4 mr = *(const float4*)&Mrow[toff];
    float4 zi = *(const float4*)&Zr[toff];
    uint2 q0 = *(const uint2*)(Qsl + col * T + toff);
    uint2 q1 = *(const uint2*)(Qsl + (16 + col) * T + toff);
    half4v a0, a1;
    a0[0] = (_Float16)(h2f(q0.x & 0xffffu) * zi.x);
    a0[1] = (_Float16)(h2f(q0.x >> 16) * zi.y);
    a0[2] = (_Float16)(h2f(q0.y & 0xffffu) * zi.z);
    a0[3] = (_Float16)(h2f(q0.y >> 16) * zi.w);
    a1[0] = (_Float16)(h2f(q1.x & 0xffffu) * zi.x);
    a1[1] = (_Float16)(h2f(q1.x >> 16) * zi.y);
    a1[2] = (_Float16)(h2f(q1.y & 0xffffu) * zi.z);
    a1[3] = (_Float16)(h2f(q1.y >> 16) * zi.w);
#pragma unroll
    for (int si = 0; si < NSW; ++si) {
      float4v s = mfma16x16x32_f16(kf, vfr[si], zero4);
      half4v pb;
      pb[0] = (_Float16)__expf(s[0] * tscale - mr.x);
      pb[1] = (_Float16)__expf(s[1] * tscale - mr.y);
      pb[2] = (_Float16)__expf(s[2] * tscale - mr.z);
      pb[3] = (_Float16)__expf(s[3] * tscale - mr.w);
      oacc[si][0] = mfma16x16x16_f16(a0, pb, oacc[si][0]);
      oacc[si][1] = mfma16x16x16_f16(a1, pb, oacc[si][1]);
    }
  }

  // --- epilogue ---
#pragma unroll
  for (int si = 0; si < NSW; ++si) {
    const int s = (w + si * 4) * 16 + col;
#pragma unroll
    for (int m0 = 0; m0 < 2; ++m0) {
#pragma unroll
      for (int r = 0; r < 4; ++r) {
        const int dd = m0 * 16 + grp * 4 + r;
        const int off = base + dd * T + s;
        float v = oacc[si][m0][r];
        if (add_src) v += add_src[off];
        outp[off] = v;
        if (diff_out) diff_out[off] = f2h(tl1_src[off] - v);
      }
    }
  }
}

// ---------- layernorm over rows of 512: y = (x-mu)*rsqrt(var+eps)*g + b -> fp16 ----------
__global__ __launch_bounds__(256) void ln_kernel(const float* __restrict__ xin,
                                                 const float* __restrict__ g,
                                                 const float* __restrict__ bb,
                                                 unsigned short* __restrict__ y) {
  const int row = blockIdx.x * 4 + (threadIdx.x >> 6);
  const int lane = threadIdx.x & 63;
  const float* xr = xin + (size_t)row * 512;
  float4 v0 = *(const float4*)&xr[lane * 8];
  float4 v1 = *(const float4*)&xr[lane * 8 + 4];
  float s = v0.x + v0.y + v0.z + v0.w + v1.x + v1.y + v1.z + v1.w;
  float q = v0.x * v0.x + v0.y * v0.y + v0.z * v0.z + v0.w * v0.w +
            v1.x * v1.x + v1.y * v1.y + v1.z * v1.z + v1.w * v1.w;
#pragma unroll
  for (int m = 1; m < 64; m <<= 1) {
    s += __shfl_xor(s, m);
    q += __shfl_xor(q, m);
  }
  const float mean = s * (1.0f / 512.0f);
  const float var = q * (1.0f / 512.0f) - mean * mean;
  const float rs = rsqrtf(var + 1e-5f);
  float4 g0 = *(const float4*)&g[lane * 8];
  float4 g1 = *(const float4*)&g[lane * 8 + 4];
  float4 b0 = *(const float4*)&bb[lane * 8];
  float4 b1 = *(const float4*)&bb[lane * 8 + 4];
  uint4 o;
  o.x = (unsigned)f2h((v0.x - mean) * rs * g0.x + b0.x) |
        ((unsigned)f2h((v0.y - mean) * rs * g0.y + b0.y) << 16);
  o.y = (unsigned)f2h((v0.z - mean) * rs * g0.z + b0.z) |
        ((unsigned)f2h((v0.w - mean) * rs * g0.w + b0.w) << 16);
  o.z = (unsigned)f2h((v1.x - mean) * rs * g1.x + b1.x) |
        ((unsigned)f2h((v1.y - mean) * rs * g1.y + b1.y) << 16);
  o.w = (unsigned)f2h((v1.z - mean) * rs * g1.z + b1.z) |
        ((unsigned)f2h((v1.w - mean) * rs * g1.w + b1.w) << 16);
  *(uint4*)&y[(size_t)row * 512 + lane * 8] = o;
}

// ---------- launch ----------
extern "C" void kernel_launch(void* const* d_in, const int* in_sizes, int n_in,
                              void* d_out, int out_size, void* d_ws, size_t ws_size,
                              hipStream_t stream) {
  const float* x = (const float*)d_in[0];
  const float* qw = (const float*)d_in[1];
  const float* qb = (const float*)d_in[2];
  const float* kw = (const float*)d_in[3];
  const float* kb = (const float*)d_in[4];
  const float* vw = (const float*)d_in[5];
  const float* vb = (const float*)d_in[6];
  const float* temp = (const float*)d_in[7];
  const float* ln_g = (const float*)d_in[8];
  const float* ln_b = (const float*)d_in[9];
  const float* fus_w = (const float*)d_in[10];
  // fus_b (d_in[11]) cancels in the 2-way softmax; num_heads (d_in[12]) fixed at 16
  float* out = (float*)d_out;

  const size_t NE = (size_t)32 * 384 * 512;  // 6291456
  const size_t WE = (size_t)5 * 512 * 512;   // 1310720

  char* p = (char*)d_ws;
  auto alloc = [&](size_t bytes) {
    char* r = p;
    p += (bytes + 255) & ~(size_t)255;
    return r;
  };
  unsigned short* xb = (unsigned short*)alloc(NE * 2);
  unsigned short* wqb = (unsigned short*)alloc(WE * 2);
  unsigned short* wkb = (unsigned short*)alloc(WE * 2);
  unsigned short* wvb = (unsigned short*)alloc(WE * 2);
  unsigned short* fwb = (unsigned short*)alloc((size_t)512 * 512 * 2);
  unsigned short* Qb = (unsigned short*)alloc(NE * 2);
  unsigned short* Kb = (unsigned short*)alloc(NE * 2);
  unsigned short* Vb = (unsigned short*)alloc(NE * 2);
  float* xres = (float*)alloc(NE * 4);  // x_ , later tl2 (in place)
  float* tl1 = (float*)alloc(NE * 4);
  unsigned short* yb = (unsigned short*)alloc(NE * 2);  // LN output, later diff (fp16)

  // converts
  cvt_f32_f16<<<(int)((NE / 4 + 255) / 256), 256, 0, stream>>>(x, xb, (int)(NE / 4));
  cvt_f32_f16<<<(int)((WE / 4 + 255) / 256), 256, 0, stream>>>(qw, wqb, (int)(WE / 4));
  cvt_f32_f16<<<(int)((WE / 4 + 255) / 256), 256, 0, stream>>>(kw, wkb, (int)(WE / 4));
  cvt_f32_f16<<<(int)((WE / 4 + 255) / 256), 256, 0, stream>>>(vw, wvb, (int)(WE / 4));
  cvt_f32_f16<<<256, 256, 0, stream>>>(fus_w, fwb, 512 * 512 / 4);

  // block 0 projections + attention -> x_ (xres)
  gemm_qkv<<<dim3(4, 96, 3), 256, 0, stream>>>(xb, wqb, wkb, wvb, qb, kb, vb, Qb, Kb, Vb, 0, 0);
  attn_kernel<384><<<dim3(16, 32, 1), 256, 0, stream>>>(Qb, Kb, Vb, temp, nullptr, xres, 0,
                                                        nullptr, nullptr);
  // blocks 1-3 (chunked) projections + attention -> tl1 = concat + x_
  gemm_qkv<<<dim3(4, 96, 3), 256, 0, stream>>>(xb, wqb, wkb, wvb, qb, kb, vb, Qb, Kb, Vb, 1, 0);
  attn_kernel<128><<<dim3(16, 32, 3), 256, 0, stream>>>(Qb, Kb, Vb, temp + 16, xres, tl1,
                                                        128 * 512, nullptr, nullptr);
  // layernorm -> y (fp16)
  ln_kernel<<<12288 / 4, 256, 0, stream>>>(tl1, ln_g, ln_b, yb);
  // block 4 projections + attention -> tl2 = out + x_ (in-place into xres), diff -> yb
  gemm_qkv<<<dim3(4, 96, 3), 256, 0, stream>>>(yb, wqb, wkb, wvb, qb, kb, vb, Qb, Kb, Vb, 0, 4);
  attn_kernel<384><<<dim3(16, 32, 1), 256, 0, stream>>>(Qb, Kb, Vb, temp + 64, xres, xres, 0,
                                                        tl1, yb);
  // fusion: out = tl2 + (tl1-tl2)*sigmoid((tl1-tl2)@fus_w^T)
  gemm_fusion<<<dim3(4, 96, 1), 256, 0, stream>>>(yb, fwb, tl1, xres, out);

  (void)in_sizes; (void)n_in; (void)out_size; (void)ws_size;
}